// Round 7
// baseline (322.439 us; speedup 1.0000x reference)
//
#include <hip/hip_runtime.h>
#include <hip/hip_bf16.h>
#include <math.h>

// Problem constants
constexpr int cB   = 4;
constexpr int cL   = 1024;
constexpr int cH   = 1024;
constexpr int cA   = 16;
constexpr int cM   = 128;
constexpr int cE   = 32;
constexpr int cR   = 992;
constexpr int cEMB = 768;
constexpr int cC   = 97;
constexpr int cN   = cB * cR;   // 3968
constexpr int cNG  = 12;        // islice groups (2 islices each)
constexpr int cPC  = 104;       // part c-stride (12 groups must fit dead ws region)

typedef unsigned short ushort;
typedef __attribute__((ext_vector_type(4))) unsigned short ushort4v;
typedef __attribute__((ext_vector_type(8))) short short8;
typedef __attribute__((ext_vector_type(4))) float float4v;
typedef __attribute__((ext_vector_type(2))) float float2v;

static __device__ inline float bf2f(ushort u) {
    unsigned v = ((unsigned)u) << 16;
    float f;
    __builtin_memcpy(&f, &v, 4);
    return f;
}
static __device__ inline ushort f2bf(float f) {
    unsigned u;
    __builtin_memcpy(&u, &f, 4);
    unsigned r = (u + 0x7FFFu + ((u >> 16) & 1u)) >> 16;
    return (ushort)r;
}

// 16B global -> LDS DMA (LDS dest: wave-uniform base + lane*16)
static __device__ inline void gld16(const ushort* src, ushort* dstbase) {
    __builtin_amdgcn_global_load_lds(
        (const __attribute__((address_space(1))) unsigned int*)src,
        (__attribute__((address_space(3))) unsigned int*)dstbase, 16, 0, 0);
}

// ---------------------------------------------------------------------------
// Generic transpose f32 -> bf16: src[z][R][C] -> dst[z][Cp][R], zero-pad c>=C
__global__ void tr_bf16_k(const float* __restrict__ src, ushort* __restrict__ dst,
                          int R, int C, int Cp) {
    int z = blockIdx.z;
    int r0 = blockIdx.x * 32, c0 = blockIdx.y * 32;
    int tx = threadIdx.x & 31, ty = threadIdx.x >> 5;  // ty 0..7
    __shared__ float tile[32][33];
    for (int p = 0; p < 4; p++) {
        int r = r0 + ty + p * 8, c = c0 + tx;
        tile[ty + p * 8][tx] = (r < R && c < C) ? src[((size_t)z * R + r) * C + c] : 0.f;
    }
    __syncthreads();
    for (int p = 0; p < 4; p++) {
        int c = c0 + ty + p * 8, r = r0 + tx;
        if (c < Cp && r < R)
            dst[((size_t)z * Cp + c) * R + r] = f2bf(tile[tx][ty + p * 8]);
    }
}

// Head+tail weight transpose in one launch (z selects which matrix)
__global__ void tr_ht_k(const float* __restrict__ Wh, const float* __restrict__ Wt,
                        ushort* __restrict__ WTh, ushort* __restrict__ WTt) {
    const float* src = blockIdx.z ? Wt : Wh;
    ushort* dst = blockIdx.z ? WTt : WTh;
    int r0 = blockIdx.x * 32, c0 = blockIdx.y * 32;
    int tx = threadIdx.x & 31, ty = threadIdx.x >> 5;
    __shared__ float tile[32][33];
    for (int p = 0; p < 4; p++) {
        int r = r0 + ty + p * 8, c = c0 + tx;
        tile[ty + p * 8][tx] = src[(size_t)r * cEMB + c];
    }
    __syncthreads();
    for (int p = 0; p < 4; p++) {
        int c = c0 + ty + p * 8, r = r0 + tx;
        dst[(size_t)c * (2 * cH) + r] = f2bf(tile[tx][ty + p * 8]);
    }
}

// ---------------------------------------------------------------------------
// Build fragment-ordered bilinear weights (16 frags per i, v3 layout):
// Wf[si][f][lane][8] bf16, f = khalf*8+ct,
// element = W[(si*64 + j)][c], j = khalf*32 + (lane>>4)*8 + jj, c = ct*16 + (lane&15)
__global__ void wf_build_k(const float* __restrict__ W, ushort* __restrict__ Wf) {
    const int si = blockIdx.x;
    const int tid = threadIdx.x;
    __shared__ ushort sWb[64 * 136];
    for (int idx = tid; idx < 64 * 128; idx += 256) {
        int r = idx >> 7, c = idx & 127;
        float v = (c < cC) ? W[((size_t)si * 64 + r) * cC + c] : 0.f;
        sWb[r * 136 + c] = f2bf(v);
    }
    __syncthreads();
#pragma unroll
    for (int p = 0; p < 4; p++) {
        int e = tid + p * 256;          // 0..1023
        int f = e >> 6, lane = e & 63;
        int g = lane >> 4, col = lane & 15;
        int khalf = f >> 3, ct = f & 7;
        int jb = khalf * 32 + g * 8;
        int c = ct * 16 + col;
        short8 v;
#pragma unroll
        for (int jj = 0; jj < 8; jj++) v[jj] = (short)sWb[(jb + jj) * 136 + c];
        *(short8*)&Wf[(((size_t)si * 16 + f) * 64 + lane) * 8] = v;
    }
}

// ---------------------------------------------------------------------------
// Kernel 1: per-(b,e) logsumexp pooling of ent_lhs; writes bf16.
__global__ void ent_pool_k(const float* __restrict__ ent_lhs, const int* __restrict__ ids,
                           ushort* __restrict__ ent_emb, int* __restrict__ counts) {
    int e = blockIdx.x, b = blockIdx.y;
    __shared__ int sid[cM];
    int tid = threadIdx.x;
    if (tid < cM) sid[tid] = ids[b * cM + tid];
    __syncthreads();
    int cnt = 0;
    for (int m = 0; m < cM; m++) cnt += (sid[m] == e) ? 1 : 0;
    if (blockIdx.z == 0 && tid == 0) counts[b * cE + e] = cnt;
    int h = blockIdx.z * 256 + tid;
    {
        float mx = -1e30f;
        for (int m = 0; m < cM; m++)
            if (sid[m] == e) mx = fmaxf(mx, ent_lhs[(size_t)(b * cM + m) * cH + h]);
        float s = 0.f;
        for (int m = 0; m < cM; m++)
            if (sid[m] == e) s += __expf(ent_lhs[(size_t)(b * cM + m) * cH + h] - mx);
        ent_emb[(size_t)(b * cE + e) * cH + h] = f2bf((cnt > 0) ? (mx + __logf(s)) : 0.f);
    }
}

// ---------------------------------------------------------------------------
// Kernel 2: ent_attn[b][e][a][l] (bf16) = segment-mean of attn
__global__ void ent_attn_k(const float* __restrict__ attn, const int* __restrict__ ids,
                           const int* __restrict__ counts, ushort* __restrict__ ent_attn) {
    int ba = blockIdx.x;
    int b = ba / cA, a = ba % cA;
    int tid = threadIdx.x;
    int l = blockIdx.y * 256 + tid;
    __shared__ int sid[cM];
    __shared__ int scnt[cE];
    __shared__ float sacc[256 * 33];
    if (tid < cM) sid[tid] = ids[b * cM + tid];
    if (tid < cE) scnt[tid] = counts[b * cE + tid];
    float* acc = &sacc[tid * 33];
    for (int e2 = 0; e2 < cE; e2++) acc[e2] = 0.f;
    __syncthreads();
    const float* ap = attn + ((size_t)(b * cA + a) * cM) * cL + l;
    for (int m = 0; m < cM; m++) acc[sid[m]] += ap[(size_t)m * cL];
    for (int e2 = 0; e2 < cE; e2++) {
        ent_attn[((size_t)(b * cE + e2) * cA + a) * cL + l] =
            f2bf(acc[e2] / (float)max(scnt[e2], 1));
    }
}

// ---------------------------------------------------------------------------
// Kernel 3: w[b][r][l] = mean_a ha*ta, normalized over l (ushort4 vectorized)
__global__ void w_k(const ushort* __restrict__ ent_attn, const int* __restrict__ hts,
                    ushort* __restrict__ w) {
    int nr = blockIdx.x;
    int b = nr / cR;
    int he = hts[nr * 2 + 0], te = hts[nr * 2 + 1];
    int tid = threadIdx.x;
    int l0 = tid * 4;
    const ushort* ha = ent_attn + ((size_t)(b * cE + he) * cA) * cL + l0;
    const ushort* ta = ent_attn + ((size_t)(b * cE + te) * cA) * cL + l0;
    float v[4] = {0.f, 0.f, 0.f, 0.f};
#pragma unroll
    for (int a = 0; a < cA; a++) {
        ushort4v hv = *(const ushort4v*)&ha[(size_t)a * cL];
        ushort4v tv = *(const ushort4v*)&ta[(size_t)a * cL];
#pragma unroll
        for (int i = 0; i < 4; i++) v[i] += bf2f(hv[i]) * bf2f(tv[i]);
    }
    float psum = 0.f;
#pragma unroll
    for (int i = 0; i < 4; i++) { v[i] *= (1.0f / cA); psum += v[i]; }
    for (int off = 32; off > 0; off >>= 1) psum += __shfl_down(psum, off, 64);
    __shared__ float red[4];
    if ((tid & 63) == 0) red[tid >> 6] = psum;
    __syncthreads();
    float tot = red[0] + red[1] + red[2] + red[3];
    float inv = 1.0f / (tot + 1e-5f);
    ushort4v o;
#pragma unroll
    for (int i = 0; i < 4; i++) o[i] = f2bf(v[i] * inv);
    *(ushort4v*)&w[(size_t)nr * cL + l0] = o;
}

// ---------------------------------------------------------------------------
// Kernel 4: rel MFMA GEMM v2 (Round-5 verified: gld16 + XOR swizzle + 2-phase)
__global__ __launch_bounds__(256) void
rel_mfma2_k(const ushort* __restrict__ wbf, const ushort* __restrict__ seqT,
            ushort* __restrict__ relbf) {
    const int b = blockIdx.z;
    const int h0 = blockIdx.x * 128, r0 = blockIdx.y * 64;
    const int tid = threadIdx.x, lane = tid & 63, wv = tid >> 6;
    const int col = lane & 15, g4 = lane >> 4;
    const int wr = wv >> 1, wc = wv & 1;   // wave tile rows [wr*32,+32) cols [wc*64,+64)

    __shared__ ushort sA[2][64 * 64];
    __shared__ ushort sB[2][128 * 64];

    const int lr = lane >> 3;              // 0..7
    const int swz = (lane & 7) ^ lr;       // source seg pre-swizzle

    const int ra0 = wv * 8 + lr, ra1 = ra0 + 32;
    const ushort* a0p = wbf + ((size_t)b * cR + min(r0 + ra0, cR - 1)) * cL + swz * 8;
    const ushort* a1p = wbf + ((size_t)b * cR + min(r0 + ra1, cR - 1)) * cL + swz * 8;
    const ushort* bptr[4];
#pragma unroll
    for (int p = 0; p < 4; p++)
        bptr[p] = seqT + ((size_t)b * cH + h0 + p * 32 + wv * 8 + lr) * cL + swz * 8;

    float4v acc[2][4];
#pragma unroll
    for (int mt = 0; mt < 2; mt++)
#pragma unroll
        for (int ct = 0; ct < 4; ct++) acc[mt][ct] = (float4v){0.f, 0.f, 0.f, 0.f};

#define REL_STAGE(kt, buf) {                                                   \
        gld16(a0p + (kt), &sA[buf][wv * 512]);                                 \
        gld16(a1p + (kt), &sA[buf][(4 + wv) * 512]);                           \
        _Pragma("unroll")                                                      \
        for (int p = 0; p < 4; p++)                                            \
            gld16(bptr[p] + (kt), &sB[buf][(p * 4 + wv) * 512]);               \
    }

    REL_STAGE(0, 0);
    __syncthreads();   // vmcnt(0) drained at barrier -> tile 0 landed
    int cur = 0;
    for (int kt = 0; kt < cL; kt += 64) {
        if (kt + 64 < cL) REL_STAGE(kt + 64, cur ^ 1);
#pragma unroll
        for (int k0 = 0; k0 < 64; k0 += 32) {
            short8 av[2];
#pragma unroll
            for (int mt = 0; mt < 2; mt++) {
                int ra = wr * 32 + mt * 16 + col;
                int sg = ((k0 >> 3) + g4) ^ (ra & 7);
                av[mt] = *(const short8*)&sA[cur][ra * 64 + sg * 8];
            }
#pragma unroll
            for (int ct = 0; ct < 4; ct++) {
                int rb = wc * 64 + ct * 16 + col;
                int sg = ((k0 >> 3) + g4) ^ (rb & 7);
                short8 bv = *(const short8*)&sB[cur][rb * 64 + sg * 8];
#pragma unroll
                for (int mt = 0; mt < 2; mt++)
                    acc[mt][ct] = __builtin_amdgcn_mfma_f32_16x16x32_bf16(
                        av[mt], bv, acc[mt][ct], 0, 0, 0);
            }
        }
        __syncthreads();   // readers done with cur; prefetch (cur^1) landed
        cur ^= 1;
    }
#undef REL_STAGE

#pragma unroll
    for (int mt = 0; mt < 2; mt++) {
#pragma unroll
        for (int ct = 0; ct < 4; ct++) {
            int h = h0 + wc * 64 + ct * 16 + col;
            int rowb = r0 + wr * 32 + mt * 16 + g4 * 4;
#pragma unroll
            for (int reg = 0; reg < 4; reg++) {
                int r = rowb + reg;
                if (r < cR)
                    relbf[((size_t)b * cR + r) * cH + h] = f2bf(acc[mt][ct][reg]);
            }
        }
    }
}

// ---------------------------------------------------------------------------
// Kernel 5: projection MFMA GEMM v3 (Round-5 verified: 2-phase 1-barrier)
__global__ __launch_bounds__(256) void
proj_mfma3_k(const ushort* __restrict__ ent_bf, const ushort* __restrict__ relbf,
             const int* __restrict__ hts,
             const ushort* __restrict__ WTh, const ushort* __restrict__ WTt,
             const float* __restrict__ head_b, const float* __restrict__ tail_b,
             ushort* __restrict__ hsp, ushort* __restrict__ tsp) {
    const int sel = blockIdx.z;
    const ushort* WTp = sel ? WTt : WTh;
    const float* bias = sel ? tail_b : head_b;
    ushort* outp = sel ? tsp : hsp;

    const int e0 = blockIdx.x * 128, n0 = blockIdx.y * 64;
    const int tid = threadIdx.x, lane = tid & 63, wv = tid >> 6;
    const int col = lane & 15, g4 = lane >> 4;
    const int wr = wv >> 1, wc = wv & 1;

    __shared__ ushort sA[2][64 * 64];
    __shared__ ushort sB[2][128 * 64];

    const int lr = lane >> 3;
    const int swz = (lane & 7) ^ lr;

    const int ra0 = wv * 8 + lr, ra1 = ra0 + 32;
    size_t eb0, eb1;
    { int n = n0 + ra0, bb = n / cR; eb0 = ((size_t)(bb * cE + hts[n * 2 + sel])) * cH; }
    { int n = n0 + ra1, bb = n / cR; eb1 = ((size_t)(bb * cE + hts[n * 2 + sel])) * cH; }
    const ushort* aent0 = ent_bf + eb0 + swz * 8;
    const ushort* aent1 = ent_bf + eb1 + swz * 8;
    const ushort* arel0 = relbf + (size_t)(n0 + ra0) * cH + swz * 8;
    const ushort* arel1 = relbf + (size_t)(n0 + ra1) * cH + swz * 8;

    const ushort* bptr[4];
#pragma unroll
    for (int p = 0; p < 4; p++)
        bptr[p] = WTp + (size_t)(e0 + p * 32 + wv * 8 + lr) * (2 * cH) + swz * 8;

    float4v acc[2][4];
#pragma unroll
    for (int mt = 0; mt < 2; mt++)
#pragma unroll
        for (int ct = 0; ct < 4; ct++) acc[mt][ct] = (float4v){0.f, 0.f, 0.f, 0.f};

#define PROJ_STAGE(kt, buf) {                                                  \
        const ushort* a0 = ((kt) < cH) ? aent0 + (kt) : arel0 + ((kt) - cH);   \
        const ushort* a1 = ((kt) < cH) ? aent1 + (kt) : arel1 + ((kt) - cH);   \
        gld16(a0, &sA[buf][wv * 512]);                                         \
        gld16(a1, &sA[buf][(4 + wv) * 512]);                                   \
        _Pragma("unroll")                                                      \
        for (int p = 0; p < 4; p++)                                            \
            gld16(bptr[p] + (kt), &sB[buf][(p * 4 + wv) * 512]);               \
    }

    PROJ_STAGE(0, 0);
    __syncthreads();
    int cur = 0;
    for (int kt = 0; kt < 2 * cH; kt += 64) {
        if (kt + 64 < 2 * cH) PROJ_STAGE(kt + 64, cur ^ 1);
#pragma unroll
        for (int k0 = 0; k0 < 64; k0 += 32) {
            short8 av[2];
#pragma unroll
            for (int mt = 0; mt < 2; mt++) {
                int ra = wr * 32 + mt * 16 + col;
                int sg = ((k0 >> 3) + g4) ^ (ra & 7);
                av[mt] = *(const short8*)&sA[cur][ra * 64 + sg * 8];
            }
#pragma unroll
            for (int ct = 0; ct < 4; ct++) {
                int rb = wc * 64 + ct * 16 + col;
                int sg = ((k0 >> 3) + g4) ^ (rb & 7);
                short8 bv = *(const short8*)&sB[cur][rb * 64 + sg * 8];
#pragma unroll
                for (int mt = 0; mt < 2; mt++)
                    acc[mt][ct] = __builtin_amdgcn_mfma_f32_16x16x32_bf16(
                        av[mt], bv, acc[mt][ct], 0, 0, 0);
            }
        }
        __syncthreads();
        cur ^= 1;
    }
#undef PROJ_STAGE

#pragma unroll
    for (int mt = 0; mt < 2; mt++) {
#pragma unroll
        for (int ct = 0; ct < 4; ct++) {
            int e = e0 + wc * 64 + ct * 16 + col;
            float bv = bias[e];
            int rowb = n0 + wr * 32 + mt * 16 + g4 * 4;
#pragma unroll
            for (int reg = 0; reg < 4; reg++)
                outp[(size_t)(rowb + reg) * cEMB + e] = f2bf(tanhf(acc[mt][ct][reg] + bv));
        }
    }
}

// ---------------------------------------------------------------------------
// Kernel 6: bilinear v12. Post-mortem v11+setprio: 61.3 µs, MfmaUtil 33 /
// VALUBusy 38 / occupancy 17% (grid 496 = 1.94 blocks/CU). Per-CU floors:
// MFMA 24 µs (pipe), VALU ~23 µs — at 2 waves/SIMD the per-wave
// MFMA(P)->acc+=hs*P dependency chain can't overlap across waves.
// v12: (a) cNG 8->12 (2 islices/grp): grid 744 = 2.9 blocks/CU, 11.6
// waves/CU (+50% TLP) at identical total L2 W-traffic (~3 Wf slices/XCD =
// 3 MB <= 4 MB L2); kb == grp so tsA is loaded ONCE per block.
// (b) setprio REMOVED (R5 measured regression 59.4->61.3).
// (c) VALU thinning: hoisted kZero C-operand, pointer-bump W addressing,
// float2v acc via __builtin_elementwise_fma (packs to v_pk_fma_f32 when the
// backend allows; plain v_fma fallback). part c-stride 104 so 12 groups of
// partials (19.8 MB) fit the dead ws region; epilogue guards c < cC.
__global__ __launch_bounds__(256) void
bil_mfma12_k(const ushort* __restrict__ hsp, const ushort* __restrict__ tsp,
             const ushort* __restrict__ Wf, float* __restrict__ part) {
    const int grp = blockIdx.x;          // 0..11 -> islices 2g, 2g+1
    const int n0 = blockIdx.y * 64;
    const int tid = threadIdx.x;
    const int lane = tid & 63, wv = tid >> 6;   // wv = column-quad 0..3
    const int col = lane & 15, g4 = lane >> 4;

    __shared__ float sHs[32 * 68];       // [i][row], stride 68 keeps 16B align

    float2v acc[4][2][2];
#pragma unroll
    for (int mt = 0; mt < 4; mt++)
#pragma unroll
        for (int ctl = 0; ctl < 2; ctl++) {
            acc[mt][ctl][0] = (float2v){0.f, 0.f};
            acc[mt][ctl][1] = (float2v){0.f, 0.f};
        }

    const float4v kZero = {0.f, 0.f, 0.f, 0.f};

    // 64 consecutive 16KB (8192-ushort) W i-blocks for this group
    const ushort* WfG = Wf + (size_t)grp * 2 * 32 * 8192;
    const ushort* wbase = WfG + ((size_t)(wv * 2) * 64 + lane) * 8;

    // ts A-fragments: kb == grp (block-constant) -> load once, live all 64 steps
    short8 tsA[4][2];
#pragma unroll
    for (int mt = 0; mt < 4; mt++)
#pragma unroll
        for (int kh = 0; kh < 2; kh++)
            tsA[mt][kh] = *(const short8*)
                &tsp[(size_t)(n0 + mt * 16 + col) * cEMB + grp * 64 + kh * 32 + g4 * 8];

#define WLOAD(dst, PTR) {                                                      \
        dst[0][0] = *(const short8*)&(PTR)[0];                                 \
        dst[0][1] = *(const short8*)&(PTR)[512];                               \
        dst[1][0] = *(const short8*)&(PTR)[4096];                              \
        dst[1][1] = *(const short8*)&(PTR)[4608];                              \
    }

#define BILSTEP(ii, w) {                                                       \
        float4v hsv[4];                                                        \
        _Pragma("unroll")                                                      \
        for (int mt = 0; mt < 4; mt++)                                         \
            hsv[mt] = *(const float4v*)&sHs[(ii) * 68 + mt * 16 + g4 * 4];     \
        _Pragma("unroll")                                                      \
        for (int ctl = 0; ctl < 2; ctl++) {                                    \
            _Pragma("unroll")                                                  \
            for (int mt = 0; mt < 4; mt++) {                                   \
                float4v P = __builtin_amdgcn_mfma_f32_16x16x32_bf16(           \
                    tsA[mt][0], w[0][ctl], kZero, 0, 0, 0);                    \
                P = __builtin_amdgcn_mfma_f32_16x16x32_bf16(                   \
                    tsA[mt][1], w[1][ctl], P, 0, 0, 0);                        \
                float2v pl = {P[0], P[1]}, ph = {P[2], P[3]};                  \
                float2v hl = {hsv[mt][0], hsv[mt][1]};                         \
                float2v hh = {hsv[mt][2], hsv[mt][3]};                         \
                acc[mt][ctl][0] = __builtin_elementwise_fma(hl, pl, acc[mt][ctl][0]); \
                acc[mt][ctl][1] = __builtin_elementwise_fma(hh, ph, acc[mt][ctl][1]); \
            }                                                                  \
        }                                                                      \
    }

    short8 wA[2][2], wB[2][2];
    const ushort* wp = wbase;
    WLOAD(wA, wp);

    for (int s = 0; s < 2; ++s) {
        const int islice = grp * 2 + s;

        __syncthreads();   // previous islice's sHs readers done
        {
            // stage hs: 64 rows x 32 i, one short8 per thread
            int row = tid & 63, seg = tid >> 6;
            short8 v = *(const short8*)
                &hsp[(size_t)(n0 + row) * cEMB + islice * 32 + seg * 8];
#pragma unroll
            for (int jj = 0; jj < 8; jj++)
                sHs[(seg * 8 + jj) * 68 + row] = bf2f((ushort)v[jj]);
        }
        __syncthreads();   // sHs visible

        // barrier-free inner loop, unroll-2 register double buffer on W
        for (int i = 0; i < 32; i += 2) {
            const int t = s * 32 + i;
            WLOAD(wB, (wp + 8192));
            BILSTEP(i, wA);
            if (t + 2 < 64) WLOAD(wA, (wp + 16384));
            BILSTEP(i + 1, wB);
            wp += 16384;
        }
    }
#undef WLOAD
#undef BILSTEP

    // epilogue: plain coalesced f32 stores; c >= cC skipped (stride 104!)
    float* pbase = part + (size_t)grp * cN * cPC;
#pragma unroll
    for (int mt = 0; mt < 4; mt++) {
#pragma unroll
        for (int ctl = 0; ctl < 2; ctl++) {
            int c = (wv * 2 + ctl) * 16 + col;
            if (c < cC) {
                int rowb = n0 + mt * 16 + g4 * 4;
                pbase[(size_t)(rowb + 0) * cPC + c] = acc[mt][ctl][0][0];
                pbase[(size_t)(rowb + 1) * cPC + c] = acc[mt][ctl][0][1];
                pbase[(size_t)(rowb + 2) * cPC + c] = acc[mt][ctl][1][0];
                pbase[(size_t)(rowb + 3) * cPC + c] = acc[mt][ctl][1][1];
            }
        }
    }
}

// ---------------------------------------------------------------------------
// Kernel 7: reduce 12 partials + bias -> out
__global__ void bil_reduce_k(const float* __restrict__ part,
                             const float* __restrict__ bil_b,
                             float* __restrict__ out) {
    int n = blockIdx.x;
    int c = threadIdx.x;            // 128 threads, c >= cC inactive
    if (c >= cC) return;
    float s = bil_b[c];
#pragma unroll
    for (int g = 0; g < cNG; g++)
        s += part[((size_t)g * cN + n) * cPC + c];
    out[(size_t)n * cC + c] = s;
}

// ---------------------------------------------------------------------------
extern "C" void kernel_launch(void* const* d_in, const int* in_sizes, int n_in,
                              void* d_out, int out_size, void* d_ws, size_t ws_size,
                              hipStream_t stream) {
    const float* seq_lhs  = (const float*)d_in[0];
    const float* ent_lhs  = (const float*)d_in[1];
    const float* attn     = (const float*)d_in[2];
    const int*   ids      = (const int*)d_in[3];
    const int*   hts      = (const int*)d_in[4];
    const float* head_W   = (const float*)d_in[5];
    const float* head_b   = (const float*)d_in[6];
    const float* tail_W   = (const float*)d_in[7];
    const float* tail_b   = (const float*)d_in[8];
    const float* bil_W    = (const float*)d_in[9];
    const float* bil_b    = (const float*)d_in[10];
    float* out = (float*)d_out;

    // workspace layout (byte offsets, 256B-aligned)
    char* ws = (char*)d_ws;
    int*    counts   = (int*)(ws + 0);             // 512 B
    ushort* ent_bf   = (ushort*)(ws + 512);        // 262144 B
    ushort* ent_attn = (ushort*)(ws + 262656);     // bf16, 4194304 B
    ushort* wbuf     = (ushort*)(ws + 4456960);    // 8126464 B
    ushort* relbf    = (ushort*)(ws + 12583424);   // 8126464 B
    ushort* hsp      = (ushort*)(ws + 20709888);   // 6094848 B
    ushort* tsp      = (ushort*)(ws + 26804736);   // 6094848 B
    ushort* Wf       = (ushort*)(ws + 32899584);   // 12582912 B
    ushort* WTh      = (ushort*)(ws + 45482496);   // 3145728 B
    ushort* WTt      = (ushort*)(ws + 48628224);   // 3145728 B
    ushort* seqT     = (ushort*)(ws + 51773952);   // 8388608 B  (end 60162560)
    // bilinear partials: 12 x 3968 x 104 x f32 = 19808256 B, overlaid on the
    // stream-dead ent_attn/wbuf/relbf region (ends 20070912 <= 20709888 OK)
    float*  part     = (float*)(ws + 262656);

    hipLaunchKernelGGL(wf_build_k, dim3(768), dim3(256), 0, stream, bil_W, Wf);
    hipLaunchKernelGGL(tr_ht_k, dim3(64, 24, 2), dim3(256), 0, stream,
                       head_W, tail_W, WTh, WTt);
    hipLaunchKernelGGL(tr_bf16_k, dim3(32, 32, cB), dim3(256), 0, stream,
                       seq_lhs, seqT, cL, cH, cH);

    hipLaunchKernelGGL(ent_pool_k, dim3(cE, cB, 4), dim3(256), 0, stream,
                       ent_lhs, ids, ent_bf, counts);
    hipLaunchKernelGGL(ent_attn_k, dim3(cB * cA, cL / 256), dim3(256), 0, stream,
                       attn, ids, counts, ent_attn);
    hipLaunchKernelGGL(w_k, dim3(cN), dim3(256), 0, stream,
                       ent_attn, hts, wbuf);
    hipLaunchKernelGGL(rel_mfma2_k, dim3(cH / 128, 16, cB), dim3(256), 0, stream,
                       wbuf, seqT, relbf);
    hipLaunchKernelGGL(proj_mfma3_k, dim3(cEMB / 128, cN / 64, 2), dim3(256), 0, stream,
                       ent_bf, relbf, hts, WTh, WTt, head_b, tail_b, hsp, tsp);
    hipLaunchKernelGGL(bil_mfma12_k, dim3(cNG, cN / 64), dim3(256), 0, stream,
                       hsp, tsp, Wf, part);
    hipLaunchKernelGGL(bil_reduce_k, dim3(cN), dim3(128), 0, stream,
                       part, bil_b, out);
}

// Round 8
// 296.341 us; speedup vs baseline: 1.0881x; 1.0881x over previous
//
#include <hip/hip_runtime.h>
#include <hip/hip_bf16.h>
#include <math.h>

// Problem constants
constexpr int cB   = 4;
constexpr int cL   = 1024;
constexpr int cH   = 1024;
constexpr int cA   = 16;
constexpr int cM   = 128;
constexpr int cE   = 32;
constexpr int cR   = 992;
constexpr int cEMB = 768;
constexpr int cC   = 97;
constexpr int cN   = cB * cR;   // 3968
constexpr int cNG  = 8;         // islice groups (3 islices each) — XCD-pinned

typedef unsigned short ushort;
typedef __attribute__((ext_vector_type(4))) unsigned short ushort4v;
typedef __attribute__((ext_vector_type(8))) short short8;
typedef __attribute__((ext_vector_type(4))) float float4v;

static __device__ inline float bf2f(ushort u) {
    unsigned v = ((unsigned)u) << 16;
    float f;
    __builtin_memcpy(&f, &v, 4);
    return f;
}
static __device__ inline ushort f2bf(float f) {
    unsigned u;
    __builtin_memcpy(&u, &f, 4);
    unsigned r = (u + 0x7FFFu + ((u >> 16) & 1u)) >> 16;
    return (ushort)r;
}

// 16B global -> LDS DMA (LDS dest: wave-uniform base + lane*16)
static __device__ inline void gld16(const ushort* src, ushort* dstbase) {
    __builtin_amdgcn_global_load_lds(
        (const __attribute__((address_space(1))) unsigned int*)src,
        (__attribute__((address_space(3))) unsigned int*)dstbase, 16, 0, 0);
}

// ---------------------------------------------------------------------------
// prep_k: fusion of 4 independent preprocessing kernels (wf_build, tr_ht,
// tr_bf16, ent_pool) into one flat-grid launch. Bodies are verbatim from the
// verified standalone kernels; only the block-index decode changed. Removes
// 3 serial launch gaps and overlaps their memory traffic.
// Ranges: [0,768) wf_build | [768,3840) tr_ht | [3840,7936) tr_bf16 |
// [7936,8448) ent_pool.
__global__ void prep_k(const float* __restrict__ bil_W,
                       const float* __restrict__ head_W,
                       const float* __restrict__ tail_W,
                       const float* __restrict__ seq_lhs,
                       const float* __restrict__ ent_lhs,
                       const int* __restrict__ ids,
                       ushort* __restrict__ Wf,
                       ushort* __restrict__ WTh, ushort* __restrict__ WTt,
                       ushort* __restrict__ seqT,
                       ushort* __restrict__ ent_bf, int* __restrict__ counts) {
    const int id = blockIdx.x;
    const int tid = threadIdx.x;
    __shared__ float tile[32][33];       // tr_ht / tr_bf16
    __shared__ ushort sWb[64 * 136];     // wf_build
    __shared__ int sid[cM];              // ent_pool

    if (id < 768) {
        // ---- wf_build ----
        const int si = id;
        for (int idx = tid; idx < 64 * 128; idx += 256) {
            int r = idx >> 7, c = idx & 127;
            float v = (c < cC) ? bil_W[((size_t)si * 64 + r) * cC + c] : 0.f;
            sWb[r * 136 + c] = f2bf(v);
        }
        __syncthreads();
#pragma unroll
        for (int p = 0; p < 4; p++) {
            int e = tid + p * 256;          // 0..1023
            int f = e >> 6, lane = e & 63;
            int g = lane >> 4, col = lane & 15;
            int khalf = f >> 3, ct = f & 7;
            int jb = khalf * 32 + g * 8;
            int c = ct * 16 + col;
            short8 v;
#pragma unroll
            for (int jj = 0; jj < 8; jj++) v[jj] = (short)sWb[(jb + jj) * 136 + c];
            *(short8*)&Wf[(((size_t)si * 16 + f) * 64 + lane) * 8] = v;
        }
    } else if (id < 3840) {
        // ---- tr_ht ----
        const int t = id - 768;
        const int bx = t & 63, by = (t >> 6) % 24, bz = t / 1536;
        const float* src = bz ? tail_W : head_W;
        ushort* dst = bz ? WTt : WTh;
        int r0 = bx * 32, c0 = by * 32;
        int tx = tid & 31, ty = tid >> 5;
        for (int p = 0; p < 4; p++) {
            int r = r0 + ty + p * 8, c = c0 + tx;
            tile[ty + p * 8][tx] = src[(size_t)r * cEMB + c];
        }
        __syncthreads();
        for (int p = 0; p < 4; p++) {
            int c = c0 + ty + p * 8, r = r0 + tx;
            dst[(size_t)c * (2 * cH) + r] = f2bf(tile[tx][ty + p * 8]);
        }
    } else if (id < 7936) {
        // ---- tr_bf16 (seq_lhs -> seqT), R=C=Cp=1024 ----
        const int t = id - 3840;
        const int bx = t & 31, by = (t >> 5) & 31, z = t >> 10;
        int r0 = bx * 32, c0 = by * 32;
        int tx = tid & 31, ty = tid >> 5;
        for (int p = 0; p < 4; p++) {
            int r = r0 + ty + p * 8, c = c0 + tx;
            tile[ty + p * 8][tx] = seq_lhs[((size_t)z * cL + r) * cH + c];
        }
        __syncthreads();
        for (int p = 0; p < 4; p++) {
            int c = c0 + ty + p * 8, r = r0 + tx;
            seqT[((size_t)z * cH + c) * cL + r] = f2bf(tile[tx][ty + p * 8]);
        }
    } else {
        // ---- ent_pool ----
        const int t = id - 7936;
        const int e = t & 31, b = (t >> 5) & 3, z = t >> 7;
        if (tid < cM) sid[tid] = ids[b * cM + tid];
        __syncthreads();
        int cnt = 0;
        for (int m = 0; m < cM; m++) cnt += (sid[m] == e) ? 1 : 0;
        if (z == 0 && tid == 0) counts[b * cE + e] = cnt;
        int h = z * 256 + tid;
        float mx = -1e30f;
        for (int m = 0; m < cM; m++)
            if (sid[m] == e) mx = fmaxf(mx, ent_lhs[(size_t)(b * cM + m) * cH + h]);
        float s = 0.f;
        for (int m = 0; m < cM; m++)
            if (sid[m] == e) s += __expf(ent_lhs[(size_t)(b * cM + m) * cH + h] - mx);
        ent_bf[(size_t)(b * cE + e) * cH + h] = f2bf((cnt > 0) ? (mx + __logf(s)) : 0.f);
    }
}

// ---------------------------------------------------------------------------
// Kernel 2: ent_attn[b][e][a][l] (bf16) = segment-mean of attn
__global__ void ent_attn_k(const float* __restrict__ attn, const int* __restrict__ ids,
                           const int* __restrict__ counts, ushort* __restrict__ ent_attn) {
    int ba = blockIdx.x;
    int b = ba / cA, a = ba % cA;
    int tid = threadIdx.x;
    int l = blockIdx.y * 256 + tid;
    __shared__ int sid[cM];
    __shared__ int scnt[cE];
    __shared__ float sacc[256 * 33];
    if (tid < cM) sid[tid] = ids[b * cM + tid];
    if (tid < cE) scnt[tid] = counts[b * cE + tid];
    float* acc = &sacc[tid * 33];
    for (int e2 = 0; e2 < cE; e2++) acc[e2] = 0.f;
    __syncthreads();
    const float* ap = attn + ((size_t)(b * cA + a) * cM) * cL + l;
    for (int m = 0; m < cM; m++) acc[sid[m]] += ap[(size_t)m * cL];
    for (int e2 = 0; e2 < cE; e2++) {
        ent_attn[((size_t)(b * cE + e2) * cA + a) * cL + l] =
            f2bf(acc[e2] / (float)max(scnt[e2], 1));
    }
}

// ---------------------------------------------------------------------------
// Kernel 3: w[b][r][l] = mean_a ha*ta, normalized over l (ushort4 vectorized)
__global__ void w_k(const ushort* __restrict__ ent_attn, const int* __restrict__ hts,
                    ushort* __restrict__ w) {
    int nr = blockIdx.x;
    int b = nr / cR;
    int he = hts[nr * 2 + 0], te = hts[nr * 2 + 1];
    int tid = threadIdx.x;
    int l0 = tid * 4;
    const ushort* ha = ent_attn + ((size_t)(b * cE + he) * cA) * cL + l0;
    const ushort* ta = ent_attn + ((size_t)(b * cE + te) * cA) * cL + l0;
    float v[4] = {0.f, 0.f, 0.f, 0.f};
#pragma unroll
    for (int a = 0; a < cA; a++) {
        ushort4v hv = *(const ushort4v*)&ha[(size_t)a * cL];
        ushort4v tv = *(const ushort4v*)&ta[(size_t)a * cL];
#pragma unroll
        for (int i = 0; i < 4; i++) v[i] += bf2f(hv[i]) * bf2f(tv[i]);
    }
    float psum = 0.f;
#pragma unroll
    for (int i = 0; i < 4; i++) { v[i] *= (1.0f / cA); psum += v[i]; }
    for (int off = 32; off > 0; off >>= 1) psum += __shfl_down(psum, off, 64);
    __shared__ float red[4];
    if ((tid & 63) == 0) red[tid >> 6] = psum;
    __syncthreads();
    float tot = red[0] + red[1] + red[2] + red[3];
    float inv = 1.0f / (tot + 1e-5f);
    ushort4v o;
#pragma unroll
    for (int i = 0; i < 4; i++) o[i] = f2bf(v[i] * inv);
    *(ushort4v*)&w[(size_t)nr * cL + l0] = o;
}

// ---------------------------------------------------------------------------
// Kernel 4: rel MFMA GEMM v2 (Round-5 verified: gld16 + XOR swizzle + 2-phase)
__global__ __launch_bounds__(256) void
rel_mfma2_k(const ushort* __restrict__ wbf, const ushort* __restrict__ seqT,
            ushort* __restrict__ relbf) {
    const int b = blockIdx.z;
    const int h0 = blockIdx.x * 128, r0 = blockIdx.y * 64;
    const int tid = threadIdx.x, lane = tid & 63, wv = tid >> 6;
    const int col = lane & 15, g4 = lane >> 4;
    const int wr = wv >> 1, wc = wv & 1;   // wave tile rows [wr*32,+32) cols [wc*64,+64)

    __shared__ ushort sA[2][64 * 64];
    __shared__ ushort sB[2][128 * 64];

    const int lr = lane >> 3;              // 0..7
    const int swz = (lane & 7) ^ lr;       // source seg pre-swizzle

    const int ra0 = wv * 8 + lr, ra1 = ra0 + 32;
    const ushort* a0p = wbf + ((size_t)b * cR + min(r0 + ra0, cR - 1)) * cL + swz * 8;
    const ushort* a1p = wbf + ((size_t)b * cR + min(r0 + ra1, cR - 1)) * cL + swz * 8;
    const ushort* bptr[4];
#pragma unroll
    for (int p = 0; p < 4; p++)
        bptr[p] = seqT + ((size_t)b * cH + h0 + p * 32 + wv * 8 + lr) * cL + swz * 8;

    float4v acc[2][4];
#pragma unroll
    for (int mt = 0; mt < 2; mt++)
#pragma unroll
        for (int ct = 0; ct < 4; ct++) acc[mt][ct] = (float4v){0.f, 0.f, 0.f, 0.f};

#define REL_STAGE(kt, buf) {                                                   \
        gld16(a0p + (kt), &sA[buf][wv * 512]);                                 \
        gld16(a1p + (kt), &sA[buf][(4 + wv) * 512]);                           \
        _Pragma("unroll")                                                      \
        for (int p = 0; p < 4; p++)                                            \
            gld16(bptr[p] + (kt), &sB[buf][(p * 4 + wv) * 512]);               \
    }

    REL_STAGE(0, 0);
    __syncthreads();   // vmcnt(0) drained at barrier -> tile 0 landed
    int cur = 0;
    for (int kt = 0; kt < cL; kt += 64) {
        if (kt + 64 < cL) REL_STAGE(kt + 64, cur ^ 1);
#pragma unroll
        for (int k0 = 0; k0 < 64; k0 += 32) {
            short8 av[2];
#pragma unroll
            for (int mt = 0; mt < 2; mt++) {
                int ra = wr * 32 + mt * 16 + col;
                int sg = ((k0 >> 3) + g4) ^ (ra & 7);
                av[mt] = *(const short8*)&sA[cur][ra * 64 + sg * 8];
            }
#pragma unroll
            for (int ct = 0; ct < 4; ct++) {
                int rb = wc * 64 + ct * 16 + col;
                int sg = ((k0 >> 3) + g4) ^ (rb & 7);
                short8 bv = *(const short8*)&sB[cur][rb * 64 + sg * 8];
#pragma unroll
                for (int mt = 0; mt < 2; mt++)
                    acc[mt][ct] = __builtin_amdgcn_mfma_f32_16x16x32_bf16(
                        av[mt], bv, acc[mt][ct], 0, 0, 0);
            }
        }
        __syncthreads();   // readers done with cur; prefetch (cur^1) landed
        cur ^= 1;
    }
#undef REL_STAGE

#pragma unroll
    for (int mt = 0; mt < 2; mt++) {
#pragma unroll
        for (int ct = 0; ct < 4; ct++) {
            int h = h0 + wc * 64 + ct * 16 + col;
            int rowb = r0 + wr * 32 + mt * 16 + g4 * 4;
#pragma unroll
            for (int reg = 0; reg < 4; reg++) {
                int r = rowb + reg;
                if (r < cR)
                    relbf[((size_t)b * cR + r) * cH + h] = f2bf(acc[mt][ct][reg]);
            }
        }
    }
}

// ---------------------------------------------------------------------------
// Kernel 5: projection MFMA GEMM v3 (Round-5 verified: 2-phase 1-barrier)
__global__ __launch_bounds__(256) void
proj_mfma3_k(const ushort* __restrict__ ent_bf, const ushort* __restrict__ relbf,
             const int* __restrict__ hts,
             const ushort* __restrict__ WTh, const ushort* __restrict__ WTt,
             const float* __restrict__ head_b, const float* __restrict__ tail_b,
             ushort* __restrict__ hsp, ushort* __restrict__ tsp) {
    const int sel = blockIdx.z;
    const ushort* WTp = sel ? WTt : WTh;
    const float* bias = sel ? tail_b : head_b;
    ushort* outp = sel ? tsp : hsp;

    const int e0 = blockIdx.x * 128, n0 = blockIdx.y * 64;
    const int tid = threadIdx.x, lane = tid & 63, wv = tid >> 6;
    const int col = lane & 15, g4 = lane >> 4;
    const int wr = wv >> 1, wc = wv & 1;

    __shared__ ushort sA[2][64 * 64];
    __shared__ ushort sB[2][128 * 64];

    const int lr = lane >> 3;
    const int swz = (lane & 7) ^ lr;

    const int ra0 = wv * 8 + lr, ra1 = ra0 + 32;
    size_t eb0, eb1;
    { int n = n0 + ra0, bb = n / cR; eb0 = ((size_t)(bb * cE + hts[n * 2 + sel])) * cH; }
    { int n = n0 + ra1, bb = n / cR; eb1 = ((size_t)(bb * cE + hts[n * 2 + sel])) * cH; }
    const ushort* aent0 = ent_bf + eb0 + swz * 8;
    const ushort* aent1 = ent_bf + eb1 + swz * 8;
    const ushort* arel0 = relbf + (size_t)(n0 + ra0) * cH + swz * 8;
    const ushort* arel1 = relbf + (size_t)(n0 + ra1) * cH + swz * 8;

    const ushort* bptr[4];
#pragma unroll
    for (int p = 0; p < 4; p++)
        bptr[p] = WTp + (size_t)(e0 + p * 32 + wv * 8 + lr) * (2 * cH) + swz * 8;

    float4v acc[2][4];
#pragma unroll
    for (int mt = 0; mt < 2; mt++)
#pragma unroll
        for (int ct = 0; ct < 4; ct++) acc[mt][ct] = (float4v){0.f, 0.f, 0.f, 0.f};

#define PROJ_STAGE(kt, buf) {                                                  \
        const ushort* a0 = ((kt) < cH) ? aent0 + (kt) : arel0 + ((kt) - cH);   \
        const ushort* a1 = ((kt) < cH) ? aent1 + (kt) : arel1 + ((kt) - cH);   \
        gld16(a0, &sA[buf][wv * 512]);                                         \
        gld16(a1, &sA[buf][(4 + wv) * 512]);                                   \
        _Pragma("unroll")                                                      \
        for (int p = 0; p < 4; p++)                                            \
            gld16(bptr[p] + (kt), &sB[buf][(p * 4 + wv) * 512]);               \
    }

    PROJ_STAGE(0, 0);
    __syncthreads();
    int cur = 0;
    for (int kt = 0; kt < 2 * cH; kt += 64) {
        if (kt + 64 < 2 * cH) PROJ_STAGE(kt + 64, cur ^ 1);
#pragma unroll
        for (int k0 = 0; k0 < 64; k0 += 32) {
            short8 av[2];
#pragma unroll
            for (int mt = 0; mt < 2; mt++) {
                int ra = wr * 32 + mt * 16 + col;
                int sg = ((k0 >> 3) + g4) ^ (ra & 7);
                av[mt] = *(const short8*)&sA[cur][ra * 64 + sg * 8];
            }
#pragma unroll
            for (int ct = 0; ct < 4; ct++) {
                int rb = wc * 64 + ct * 16 + col;
                int sg = ((k0 >> 3) + g4) ^ (rb & 7);
                short8 bv = *(const short8*)&sB[cur][rb * 64 + sg * 8];
#pragma unroll
                for (int mt = 0; mt < 2; mt++)
                    acc[mt][ct] = __builtin_amdgcn_mfma_f32_16x16x32_bf16(
                        av[mt], bv, acc[mt][ct], 0, 0, 0);
            }
        }
        __syncthreads();
        cur ^= 1;
    }
#undef PROJ_STAGE

#pragma unroll
    for (int mt = 0; mt < 2; mt++) {
#pragma unroll
        for (int ct = 0; ct < 4; ct++) {
            int e = e0 + wc * 64 + ct * 16 + col;
            float bv = bias[e];
            int rowb = n0 + wr * 32 + mt * 16 + g4 * 4;
#pragma unroll
            for (int reg = 0; reg < 4; reg++)
                outp[(size_t)(rowb + reg) * cEMB + e] = f2bf(tanhf(acc[mt][ct][reg] + bv));
        }
    }
}

// ---------------------------------------------------------------------------
// Kernel 6: bilinear v13 = v11 (Round-3/4 verified: cNG=8 XCD-pinned,
// barrier-free inner loop, no setprio) + the one v12 piece that was pure
// win: kZero as the first MFMA's C operand (kills per-step P-zeroing VALU,
// numerically identical). v12's cNG=12 REVERTED: it broke blockIdx%8 XCD
// pinning (FETCH doubled 14->28 MB = one extra HBM pass of Wf) and grew the
// partial buffer; measured 61.3->62.8 regression.
__global__ __launch_bounds__(256) void
bil_mfma13_k(const ushort* __restrict__ hsp, const ushort* __restrict__ tsp,
             const ushort* __restrict__ Wf, float* __restrict__ part) {
    const int grp = blockIdx.x;          // 0..7 -> islices 3g..3g+2 (XCD-pinned)
    const int n0 = blockIdx.y * 64;
    const int tid = threadIdx.x;
    const int lane = tid & 63, wv = tid >> 6;   // wv = column-quad 0..3
    const int col = lane & 15, g4 = lane >> 4;

    __shared__ float sHs[32 * 68];       // [i][row], stride 68 keeps 16B align

    float4v acc[4][2];
#pragma unroll
    for (int mt = 0; mt < 4; mt++)
#pragma unroll
        for (int ctl = 0; ctl < 2; ctl++) acc[mt][ctl] = (float4v){0.f, 0.f, 0.f, 0.f};

    const float4v kZero = {0.f, 0.f, 0.f, 0.f};

    // 96 consecutive 16KB (8192-ushort) W i-blocks for this group
    const ushort* WfG = Wf + (size_t)grp * 3 * 32 * 8192;
    const ushort* wbase = WfG + ((size_t)(wv * 2) * 64 + lane) * 8;

#define WLOAD(dst, t) {                                                        \
        const ushort* _p = wbase + (size_t)(t) * 8192;                         \
        dst[0][0] = *(const short8*)&_p[0];                                    \
        dst[0][1] = *(const short8*)&_p[512];                                  \
        dst[1][0] = *(const short8*)&_p[4096];                                 \
        dst[1][1] = *(const short8*)&_p[4608];                                 \
    }

#define BILSTEP(ii, w) {                                                       \
        float4v hsv[4];                                                        \
        _Pragma("unroll")                                                      \
        for (int mt = 0; mt < 4; mt++)                                         \
            hsv[mt] = *(const float4v*)&sHs[(ii) * 68 + mt * 16 + g4 * 4];     \
        _Pragma("unroll")                                                      \
        for (int ctl = 0; ctl < 2; ctl++) {                                    \
            _Pragma("unroll")                                                  \
            for (int mt = 0; mt < 4; mt++) {                                   \
                float4v P = __builtin_amdgcn_mfma_f32_16x16x32_bf16(           \
                    tsA[mt][0], w[0][ctl], kZero, 0, 0, 0);                    \
                P = __builtin_amdgcn_mfma_f32_16x16x32_bf16(                   \
                    tsA[mt][1], w[1][ctl], P, 0, 0, 0);                        \
                acc[mt][ctl] += hsv[mt] * P;                                   \
            }                                                                  \
        }                                                                      \
    }

    short8 tsA[4][2];
    short8 wA[2][2], wB[2][2];
    WLOAD(wA, 0);

    for (int s = 0; s < 3; ++s) {
        const int islice = grp * 3 + s;
        const int kb = islice >> 1;

        __syncthreads();   // previous islice's sHs readers done
        {
            // stage hs: 64 rows x 32 i, one short8 per thread
            int row = tid & 63, seg = tid >> 6;
            short8 v = *(const short8*)
                &hsp[(size_t)(n0 + row) * cEMB + islice * 32 + seg * 8];
#pragma unroll
            for (int jj = 0; jj < 8; jj++)
                sHs[(seg * 8 + jj) * 68 + row] = bf2f((ushort)v[jj]);
        }
        // ts A-fragments for this islice (registers, live for 32 steps)
#pragma unroll
        for (int mt = 0; mt < 4; mt++)
#pragma unroll
            for (int kh = 0; kh < 2; kh++)
                tsA[mt][kh] = *(const short8*)
                    &tsp[(size_t)(n0 + mt * 16 + col) * cEMB
                         + kb * 64 + kh * 32 + g4 * 8];
        __syncthreads();   // sHs visible

        // barrier-free inner loop, unroll-2 register double buffer on W
        for (int i = 0; i < 32; i += 2) {
            const int t = s * 32 + i;
            WLOAD(wB, t + 1);
            BILSTEP(i, wA);
            if (t + 2 < 96) WLOAD(wA, t + 2);
            BILSTEP(i + 1, wB);
        }
    }
#undef WLOAD
#undef BILSTEP

    // epilogue: plain coalesced f32 stores (c padded to 128; c>=97 is junk
    // the reduce kernel never reads)
    float* pbase = part + (size_t)grp * cN * 128;
#pragma unroll
    for (int mt = 0; mt < 4; mt++) {
#pragma unroll
        for (int ctl = 0; ctl < 2; ctl++) {
            int c = (wv * 2 + ctl) * 16 + col;
            int rowb = n0 + mt * 16 + g4 * 4;
#pragma unroll
            for (int reg = 0; reg < 4; reg++)
                pbase[(size_t)(rowb + reg) * 128 + c] = acc[mt][ctl][reg];
        }
    }
}

// ---------------------------------------------------------------------------
// Kernel 7: reduce 8 partials + bias -> out
__global__ void bil_reduce_k(const float* __restrict__ part,
                             const float* __restrict__ bil_b,
                             float* __restrict__ out) {
    int n = blockIdx.x;
    int c = threadIdx.x;            // 128 threads, c >= cC inactive
    if (c >= cC) return;
    float s = bil_b[c];
#pragma unroll
    for (int g = 0; g < cNG; g++)
        s += part[((size_t)g * cN + n) * 128 + c];
    out[(size_t)n * cC + c] = s;
}

// ---------------------------------------------------------------------------
extern "C" void kernel_launch(void* const* d_in, const int* in_sizes, int n_in,
                              void* d_out, int out_size, void* d_ws, size_t ws_size,
                              hipStream_t stream) {
    const float* seq_lhs  = (const float*)d_in[0];
    const float* ent_lhs  = (const float*)d_in[1];
    const float* attn     = (const float*)d_in[2];
    const int*   ids      = (const int*)d_in[3];
    const int*   hts      = (const int*)d_in[4];
    const float* head_W   = (const float*)d_in[5];
    const float* head_b   = (const float*)d_in[6];
    const float* tail_W   = (const float*)d_in[7];
    const float* tail_b   = (const float*)d_in[8];
    const float* bil_W    = (const float*)d_in[9];
    const float* bil_b    = (const float*)d_in[10];
    float* out = (float*)d_out;

    // workspace layout (byte offsets, 256B-aligned)
    char* ws = (char*)d_ws;
    int*    counts   = (int*)(ws + 0);             // 512 B
    ushort* ent_bf   = (ushort*)(ws + 512);        // 262144 B
    ushort* ent_attn = (ushort*)(ws + 262656);     // bf16, 4194304 B
    ushort* wbuf     = (ushort*)(ws + 4456960);    // 8126464 B
    ushort* relbf    = (ushort*)(ws + 12583424);   // 8126464 B
    ushort* hsp      = (ushort*)(ws + 20709888);   // 6094848 B
    ushort* tsp      = (ushort*)(ws + 26804736);   // 6094848 B
    ushort* Wf       = (ushort*)(ws + 32899584);   // 12582912 B
    ushort* WTh      = (ushort*)(ws + 45482496);   // 3145728 B
    ushort* WTt      = (ushort*)(ws + 48628224);   // 3145728 B
    ushort* seqT     = (ushort*)(ws + 51773952);   // 8388608 B  (end 60162560)
    // bilinear partials: 8 x 3968 x 128 x f32 = 16252928 B, overlaid on the
    // stream-dead ent_attn/wbuf/relbf region (all consumed before bil launch)
    float*  part     = (float*)(ws + 262656);

    hipLaunchKernelGGL(prep_k, dim3(8448), dim3(256), 0, stream,
                       bil_W, head_W, tail_W, seq_lhs, ent_lhs, ids,
                       Wf, WTh, WTt, seqT, ent_bf, counts);
    hipLaunchKernelGGL(ent_attn_k, dim3(cB * cA, cL / 256), dim3(256), 0, stream,
                       attn, ids, counts, ent_attn);
    hipLaunchKernelGGL(w_k, dim3(cN), dim3(256), 0, stream,
                       ent_attn, hts, wbuf);
    hipLaunchKernelGGL(rel_mfma2_k, dim3(cH / 128, 16, cB), dim3(256), 0, stream,
                       wbuf, seqT, relbf);
    hipLaunchKernelGGL(proj_mfma3_k, dim3(cEMB / 128, cN / 64, 2), dim3(256), 0, stream,
                       ent_bf, relbf, hts, WTh, WTt, head_b, tail_b, hsp, tsp);
    hipLaunchKernelGGL(bil_mfma13_k, dim3(cNG, cN / 64), dim3(256), 0, stream,
                       hsp, tsp, Wf, part);
    hipLaunchKernelGGL(bil_reduce_k, dim3(cN), dim3(128), 0, stream,
                       part, bil_b, out);
}